// Round 3
// 112.390 us; speedup vs baseline: 1.0667x; 1.0667x over previous
//
#include <hip/hip_runtime.h>

// SINDy: out[65536,32] = Theta(z)[65536,6545] @ (Xi*Xi_mask)[6545,32]
// Round-20: fp16 MFMA path (R18/R19) + B-feed via REGISTER double-buffer
// from global, replacing the global_load_lds ring entirely.
//  - Tripwire failure in R19 = run-to-run divergence. Only candidate
//    mechanism: the LDS-DMA ring + vmcnt(0) handshake (R15/R16 already
//    showed run-varying garbage; R17 passed once with a longer iteration
//    that masked the window). fp16 shortened the iteration and re-exposed
//    it -> drop the mechanism, not the theory.
//  - B is consumed PER-LANE (bring[kh][slot][lane] -> VGPR -> MFMA B).
//    The LDS bounce never crossed lanes: direct global_load_dwordx4 into
//    a 2-chunk register pipeline is strictly better (no ds_read_b128 x2,
//    no DMA issue x2, no vmcnt(0) hard drain, -16 KB LDS, compiler-
//    managed counted waits). B is L2-resident (565 KB), ~200cy loads
//    covered by one iteration at 4 resident waves.
//  - fp16 rationale (R18): SIMD issue saturation at 4 waves/SIMD; A-build
//    was 4 pk_mul_f32 + 4 v_perm per MFMA. Now: pre-packed z octets
//    (amortized per segment) + per MFMA 1 v_cvt_pkrtz + 4 v_pk_mul_f16.
//  - Numerics: fp16 (11-bit) replaces truncated bf16 (8-bit) on A and RNE
//    bf16 on B -> error should not grow. |theta| <= ~170 << 65504.
// MFMA 32x32x16 layouts (dtype-independent, verified rounds 1-14):
//   A[m][k]: m=lane&31, k=(lane>>5)*8+jj   (reg q: lo=k 2q, hi=k 2q+1)
//   B[k][n]: n=lane&31, k=(lane>>5)*8+jj
//   C/D:     col=lane&31, row=(reg&3)+8*(reg>>2)+4*(lane>>5)

#define Z 32
#define ROWS 65536
#define NBLK (ROWS / 64)         // 1024 blocks: 2 tiles x 4 k-splits (4 waves)

#define NCHUNK 552               // quarters: 36 + 84 + 160 + 272
#define NGRAN (NCHUNK * 2)
#define NGP 1120                 // padded mg table (overreads -> 0)
#define KSPAN 138                // chunks per k-split (552/4)

typedef float f32x16 __attribute__((ext_vector_type(16)));
typedef _Float16 h2 __attribute__((ext_vector_type(2)));
typedef _Float16 h8 __attribute__((ext_vector_type(8)));

// cvt_pkrtz returns __fp16x2 — bit_cast to the _Float16 vector world
__device__ __forceinline__ h2 pkrtz(float a, float b) {
    return __builtin_bit_cast(h2, __builtin_amdgcn_cvt_pkrtz(a, b));
}

struct Sched {
    unsigned mg[NGP];          // (i*256) | (j*256)<<16 byte offs into zs[k][2][32]; pad=0
    short rt[NGRAN * 8];       // library row per (granule, jj), -1 = pad
    int nq[4];
};

constexpr Sched make_sched() {
    Sched s{};
    short gi[NGP] = {}, gj[NGP] = {};
    char gt[NGP] = {}, gq[NGP] = {};
    int tidx[32][32] = {}, pidx[32] = {};
    {
        int n = 0;
        for (int a = 0; a < 32; ++a)
            for (int b = a; b < 32; ++b) { tidx[a][b] = n; n += 32 - b; }
        for (int i = 0; i < 32; ++i) pidx[i] = i * 32 - i * (i - 1) / 2;
    }
    int g = 0;
    for (int q = 0; q < 4; ++q) {
        int g0 = g;
        // triples (a<=b): granule covers k in [8q,8q+8) for k>=b -> b>>3 <= q
        for (int b = 0; b < 32; ++b)
            if ((b >> 3) <= q)
                for (int a = 0; a <= b; ++a) { gi[g]=(short)a; gj[g]=(short)b; gt[g]=0; gq[g]=(char)q; ++g; }
        // pairs (b,32): theta = z_b*z_k, valid k<=b -> b>>3 >= q
        for (int b = 0; b < 32; ++b)
            if ((b >> 3) >= q) { gi[g]=(short)b; gj[g]=32; gt[g]=1; gq[g]=(char)q; ++g; }
        // linear: theta = z_k
        gi[g]=32; gj[g]=32; gt[g]=2; gq[g]=(char)q; ++g;
        // pad quarter to a multiple of 8 granules (4 chunks)
        while ((g - g0) & 7) { gi[g]=32; gj[g]=32; gt[g]=3; gq[g]=(char)q; ++g; }
        s.nq[q] = (g - g0) / 2;
    }
    for (int gg = 0; gg < NGRAN; ++gg) {
        s.mg[gg] = ((unsigned)gi[gg] * 256u) | (((unsigned)gj[gg] * 256u) << 16);
        int i = gi[gg], j = gj[gg], ty = gt[gg], q = gq[gg];
        for (int jj = 0; jj < 8; ++jj) {
            int k = 8 * q + jj, row = -1;
            if (ty == 0)      { if (k >= j) row = 561 + tidx[i][j] + (k - j); }   // triple (i,j,k)
            else if (ty == 1) { if (k <= i) row = 33 + pidx[k] + (i - k); }       // pair (k,i)
            else if (ty == 2) { row = 1 + k; }                                    // linear z_k
            s.rt[gg * 8 + jj] = (short)row;
        }
    }
    // [NGRAN,NGP): mg stays 0 -> pipeline overreads hit zs[0][0][m], never used
    return s;
}
constexpr Sched S = make_sched();
static_assert(S.nq[0] == 36 && S.nq[1] == 84 && S.nq[2] == 160 && S.nq[3] == 272, "chunk counts");

// ---- prep (R7-proven structure): coalesced, block per 4 granules; B -> fp16 RNE ----
__global__ void sindy_prep(const float* __restrict__ Xi,
                           const float* __restrict__ Xi_mask,
                           uint2* __restrict__ Bp2, size_t ws_size) {
    __shared__ unsigned short sh[8][32];
    const int tid = threadIdx.x;
    const int jj = tid >> 5, n = tid & 31;
#pragma unroll
    for (int pass = 0; pass < 4; ++pass) {
        int g = blockIdx.x * 4 + pass;
        int row = S.rt[g * 8 + jj];
        float f = 0.0f;
        if (row >= 0) f = Xi[row * Z + n] * Xi_mask[row * Z + n];
        _Float16 hh = (_Float16)f;                       // RNE f32->f16
        sh[jj][n] = __builtin_bit_cast(unsigned short, hh);
        __syncthreads();
        if (tid < 64) {
            int n2 = tid & 31, rep = tid >> 5;
            unsigned v0 = sh[4*rep+0][n2], v1 = sh[4*rep+1][n2];
            unsigned v2 = sh[4*rep+2][n2], v3 = sh[4*rep+3][n2];
            int c = g >> 1, h = g & 1;
            size_t idx = ((size_t)c * 64 + h * 32 + n2) * 2 + rep;
            if ((idx + 1) * 8 <= ws_size)
                Bp2[idx] = uint2{v0 | (v1 << 16), v2 | (v3 << 16)};
        }
        __syncthreads();
    }
}

// ---- main: block = 2 tiles x 4 k-splits; wave = BOTH tiles, one k-split ----
__global__ __launch_bounds__(256, 4) void sindy_mfma(const float* __restrict__ z,
                                                     const float* __restrict__ Xi,
                                                     const float* __restrict__ Xi_mask,
                                                     const uint4* __restrict__ Bp,
                                                     float* __restrict__ out) {
    const int lane = threadIdx.x & 63;
    const int kh = threadIdx.x >> 6;     // k-split 0..3 (= wave id)
    const int m = lane & 31;
    const int half = lane >> 5;
    const long R = (long)blockIdx.x * 64;   // rows of tile0; tile1 = R+32

    __shared__ float zs[33][2][32];      // interleaved: zs[k][tile][m]; bank = m
    __shared__ float cs[2][32][32];      // sequential-add combine (2 tiles)
    __shared__ unsigned mg_sh[NGP];

    for (int t = threadIdx.x; t < NGP; t += 256) mg_sh[t] = S.mg[t];
    // stage z for 64 rows (coalesced float4 reads)
    for (int idx = threadIdx.x; idx < 512; idx += 256) {
        int row = idx >> 3, q4 = idx & 7;
        float4 v = ((const float4*)(z + (R + row) * Z))[q4];
        int t = row >> 5, mm = row & 31;
        zs[4*q4+0][t][mm] = v.x; zs[4*q4+1][t][mm] = v.y;
        zs[4*q4+2][t][mm] = v.z; zs[4*q4+3][t][mm] = v.w;
    }
    if (threadIdx.x < 64) zs[32][threadIdx.x >> 5][threadIdx.x & 31] = 1.0f;  // z~[32]=1
    __syncthreads();

    const int c0 = kh * KSPAN;
    const char* zmb = (const char*)&zs[0][0][0] + 4 * m;   // tile0; tile1 = +128
    const unsigned* mgh = mg_sh + half;
    const uint4* bpl = Bp + lane;

    // B register double-buffer: bufA = chunk c, bufB = chunk c+1.
    // Plain global loads (L2-resident); compiler inserts counted vmcnt waits.
    uint4 bufA = bpl[(size_t)(c0 + 0) * 64];
    uint4 bufB = bpl[(size_t)(c0 + 1) * 64];

    // prime shallow pipeline (plain scalars, single scope — R9/R13-proven)
    unsigned u0 = mgh[2*c0], u1 = mgh[2*c0+2];
    float pA0, pA1, pB0, pB1;
    {
        float i0 = *(const float*)(zmb + (u0 & 0xFFFFu)), i1 = *(const float*)(zmb + (u0 & 0xFFFFu) + 128);
        float j0 = *(const float*)(zmb + (u0 >> 16)),     j1 = *(const float*)(zmb + (u0 >> 16) + 128);
        pA0 = i0 * j0; pA1 = i1 * j1;
        float e0 = *(const float*)(zmb + (u1 & 0xFFFFu)), e1 = *(const float*)(zmb + (u1 & 0xFFFFu) + 128);
        float f0 = *(const float*)(zmb + (u1 >> 16)),     f1 = *(const float*)(zmb + (u1 >> 16) + 128);
        pB0 = e0 * f0; pB1 = e1 * f1;
    }
    unsigned w0s = mgh[2*c0+4], w1s = mgh[2*c0+6];

    f32x16 acc0 = {}, acc1 = {};

    auto seg = [&](int Q, int cbeg, int cfin) {
        // this quarter's z octets for both tiles, pre-packed to fp16 pairs
        // (RTZ; 11-bit trunc << old 8-bit bf16 trunc). reg q: lo=k 2q, hi=k 2q+1.
        const char* zq = zmb + Q * 2048;
        h2 zA0, zA1, zA2, zA3, zB0, zB1, zB2, zB3;
        {
            float a0 = *(const float*)(zq +    0), a1 = *(const float*)(zq +  256);
            float a2 = *(const float*)(zq +  512), a3 = *(const float*)(zq +  768);
            float a4 = *(const float*)(zq + 1024), a5 = *(const float*)(zq + 1280);
            float a6 = *(const float*)(zq + 1536), a7 = *(const float*)(zq + 1792);
            float b0 = *(const float*)(zq +  128), b1 = *(const float*)(zq +  384);
            float b2 = *(const float*)(zq +  640), b3 = *(const float*)(zq +  896);
            float b4 = *(const float*)(zq + 1152), b5 = *(const float*)(zq + 1408);
            float b6 = *(const float*)(zq + 1664), b7 = *(const float*)(zq + 1920);
            zA0 = pkrtz(a0, a1); zA1 = pkrtz(a2, a3);
            zA2 = pkrtz(a4, a5); zA3 = pkrtz(a6, a7);
            zB0 = pkrtz(b0, b1); zB1 = pkrtz(b2, b3);
            zB2 = pkrtz(b4, b5); zB3 = pkrtz(b6, b7);
        }

        auto mfma0 = [&](float pp, const uint4& bv) {   // tile0
            h2 p2 = pkrtz(pp, pp);
            union { h2 h[4]; h8 v; } a;
            a.h[0] = p2 * zA0; a.h[1] = p2 * zA1;
            a.h[2] = p2 * zA2; a.h[3] = p2 * zA3;
            union { uint4 v; h8 h; } b; b.v = bv;
            acc0 = __builtin_amdgcn_mfma_f32_32x32x16_f16(a.v, b.h, acc0, 0, 0, 0);
        };
        auto mfma1 = [&](float pp, const uint4& bv) {   // tile1
            h2 p2 = pkrtz(pp, pp);
            union { h2 h[4]; h8 v; } a;
            a.h[0] = p2 * zB0; a.h[1] = p2 * zB1;
            a.h[2] = p2 * zB2; a.h[3] = p2 * zB3;
            union { uint4 v; h8 h; } b; b.v = bv;
            acc1 = __builtin_amdgcn_mfma_f32_32x32x16_f16(a.v, b.h, acc1, 0, 0, 0);
        };

        for (int c = cbeg; c < cfin; c += 2) {
            // top: issue global loads for the NEXT pair (c+2, c+3).
            // Clamped at the table end (values then unused).
            int l2 = c + 2, l3 = c + 3;
            int s2 = l2 < NCHUNK ? l2 : NCHUNK - 1;
            int s3 = l3 < NCHUNK ? l3 : NCHUNK - 1;
            uint4 nA = bpl[(size_t)s2 * 64];
            uint4 nB = bpl[(size_t)s3 * 64];
            // stage 1: mg for iter+2 (pad absorbs overread)
            unsigned nw0 = mgh[2*c+8], nw1 = mgh[2*c+10];
            // stage 2: z reads for iter+1 — tile pairs 128 B apart (ds_read2)
            float a0i = *(const float*)(zmb + (w0s & 0xFFFFu));
            float a1i = *(const float*)(zmb + (w0s & 0xFFFFu) + 128);
            float a0j = *(const float*)(zmb + (w0s >> 16));
            float a1j = *(const float*)(zmb + (w0s >> 16) + 128);
            float b0i = *(const float*)(zmb + (w1s & 0xFFFFu));
            float b1i = *(const float*)(zmb + (w1s & 0xFFFFu) + 128);
            float b0j = *(const float*)(zmb + (w1s >> 16));
            float b1j = *(const float*)(zmb + (w1s >> 16) + 128);
            // 4 MFMAs: 2 chunks x 2 tiles, B shared per chunk
            mfma0(pA0, bufA); mfma1(pA1, bufA);
            mfma0(pB0, bufB); mfma1(pB1, bufB);
            // retire products + mg + B double-buffer
            pA0 = a0i * a0j; pA1 = a1i * a1j; pB0 = b0i * b0j; pB1 = b1i * b1j;
            w0s = nw0; w1s = nw1;
            bufA = nA; bufB = nB;
        }
    };

    // quarter-aligned pieces of this wave's [c0, c0+138) range
    if (kh == 0)      { seg(0,   0,  36); seg(1,  36, 120); seg(2, 120, 138); }
    else if (kh == 1) { seg(2, 138, 276); }
    else if (kh == 2) { seg(2, 276, 280); seg(3, 280, 414); }
    else              { seg(3, 414, 552); }

    // sequential-add combine: kh3 writes, kh2/kh1 add, kh0 finishes
    if (kh == 3) {
#pragma unroll
        for (int r = 0; r < 16; ++r) {
            int row = (r & 3) + 8 * (r >> 2) + 4 * half;
            cs[0][row][m] = acc0[r]; cs[1][row][m] = acc1[r];
        }
    }
    __syncthreads();
    if (kh == 2) {
#pragma unroll
        for (int r = 0; r < 16; ++r) {
            int row = (r & 3) + 8 * (r >> 2) + 4 * half;
            cs[0][row][m] += acc0[r]; cs[1][row][m] += acc1[r];
        }
    }
    __syncthreads();
    if (kh == 1) {
#pragma unroll
        for (int r = 0; r < 16; ++r) {
            int row = (r & 3) + 8 * (r >> 2) + 4 * half;
            cs[0][row][m] += acc0[r]; cs[1][row][m] += acc1[r];
        }
    }
    __syncthreads();
    if (kh == 0) {
        const float bias = Xi[m] * Xi_mask[m];   // library row 0 (ones), col n = m
        float* o0 = out + R * Z;
        float* o1 = out + (R + 32) * Z;
#pragma unroll
        for (int r = 0; r < 16; ++r) {
            int row = (r & 3) + 8 * (r >> 2) + 4 * half;
            o0[row * Z + m] = acc0[r] + cs[0][row][m] + bias;
            o1[row * Z + m] = acc1[r] + cs[1][row][m] + bias;
        }
    }
}

extern "C" void kernel_launch(void* const* d_in, const int* in_sizes, int n_in,
                              void* d_out, int out_size, void* d_ws, size_t ws_size,
                              hipStream_t stream) {
    const float* z       = (const float*)d_in[0];
    const float* Xi      = (const float*)d_in[1];
    const float* Xi_mask = (const float*)d_in[2];
    // d_in[3]=z_mean, d_in[4]=z_std: unused by the reference
    float* out = (float*)d_out;
    uint4* Bp  = (uint4*)d_ws;   // NCHUNK*64*16 = 565,248 bytes

    sindy_prep<<<NGRAN / 4, 256, 0, stream>>>(Xi, Xi_mask, (uint2*)d_ws, ws_size);
    sindy_mfma<<<NBLK, 256, 0, stream>>>(z, Xi, Xi_mask, Bp, out);
}

// Round 5
// 108.866 us; speedup vs baseline: 1.1013x; 1.0324x over previous
//
#include <hip/hip_runtime.h>

// SINDy: out[65536,32] = Theta(z)[65536,6545] @ (Xi*Xi_mask)[6545,32]
// Round-22 = Round-21 resubmit (R21 never ran: GPU acquisition timeout).
// VALU-trim package on R20 (fp16 MFMA + reg double-buffer B).
//  - R20 post-mortem: VALUBusy 41% -> ~87 VALU insts/iter vs ~46 hand-count.
//    Overhead identified: (a) min-clamp on B-load indices defeats strength
//    reduction (64-bit mul/add + cmp/cndmask ~14 VALU/iter); (b) rolled loop
//    rotates bufA/bufB/pA*/w* via v_mov (~14/iter); (c) re-derived mg addrs.
//  - Fixes: marching pointers (bptr += 128, 2nd load at +1024B imm offset;
//    mgp += 4, ds_read2 pair), clamp removed -- the only OOB case was kh3's
//    last iteration whose loaded values are DISCARDED; that iteration is now
//    peeled (consume-only, no loads). #pragma unroll 2 for modulo renaming.
//  - MFMA floor: 37.1 GFLOP (26% pad) / 2.4 PF = ~15 us. Wall 49 us; VALU is
//    the largest consumer -> cut it.
// MFMA 32x32x16 layouts (dtype-independent, verified rounds 1-14):
//   A[m][k]: m=lane&31, k=(lane>>5)*8+jj   (reg q: lo=k 2q, hi=k 2q+1)
//   B[k][n]: n=lane&31, k=(lane>>5)*8+jj
//   C/D:     col=lane&31, row=(reg&3)+8*(reg>>2)+4*(lane>>5)

#define Z 32
#define ROWS 65536
#define NBLK (ROWS / 64)         // 1024 blocks: 2 tiles x 4 k-splits (4 waves)

#define NCHUNK 552               // quarters: 36 + 84 + 160 + 272
#define NGRAN (NCHUNK * 2)
#define NGP 1120                 // padded mg table (overreads -> 0)
#define KSPAN 138                // chunks per k-split (552/4)

typedef float f32x16 __attribute__((ext_vector_type(16)));
typedef _Float16 h2 __attribute__((ext_vector_type(2)));
typedef _Float16 h8 __attribute__((ext_vector_type(8)));

// cvt_pkrtz returns __fp16x2 — bit_cast to the _Float16 vector world
__device__ __forceinline__ h2 pkrtz(float a, float b) {
    return __builtin_bit_cast(h2, __builtin_amdgcn_cvt_pkrtz(a, b));
}

struct Sched {
    unsigned mg[NGP];          // (i*256) | (j*256)<<16 byte offs into zs[k][2][32]; pad=0
    short rt[NGRAN * 8];       // library row per (granule, jj), -1 = pad
    int nq[4];
};

constexpr Sched make_sched() {
    Sched s{};
    short gi[NGP] = {}, gj[NGP] = {};
    char gt[NGP] = {}, gq[NGP] = {};
    int tidx[32][32] = {}, pidx[32] = {};
    {
        int n = 0;
        for (int a = 0; a < 32; ++a)
            for (int b = a; b < 32; ++b) { tidx[a][b] = n; n += 32 - b; }
        for (int i = 0; i < 32; ++i) pidx[i] = i * 32 - i * (i - 1) / 2;
    }
    int g = 0;
    for (int q = 0; q < 4; ++q) {
        int g0 = g;
        // triples (a<=b): granule covers k in [8q,8q+8) for k>=b -> b>>3 <= q
        for (int b = 0; b < 32; ++b)
            if ((b >> 3) <= q)
                for (int a = 0; a <= b; ++a) { gi[g]=(short)a; gj[g]=(short)b; gt[g]=0; gq[g]=(char)q; ++g; }
        // pairs (b,32): theta = z_b*z_k, valid k<=b -> b>>3 >= q
        for (int b = 0; b < 32; ++b)
            if ((b >> 3) >= q) { gi[g]=(short)b; gj[g]=32; gt[g]=1; gq[g]=(char)q; ++g; }
        // linear: theta = z_k
        gi[g]=32; gj[g]=32; gt[g]=2; gq[g]=(char)q; ++g;
        // pad quarter to a multiple of 8 granules (4 chunks)
        while ((g - g0) & 7) { gi[g]=32; gj[g]=32; gt[g]=3; gq[g]=(char)q; ++g; }
        s.nq[q] = (g - g0) / 2;
    }
    for (int gg = 0; gg < NGRAN; ++gg) {
        s.mg[gg] = ((unsigned)gi[gg] * 256u) | (((unsigned)gj[gg] * 256u) << 16);
        int i = gi[gg], j = gj[gg], ty = gt[gg], q = gq[gg];
        for (int jj = 0; jj < 8; ++jj) {
            int k = 8 * q + jj, row = -1;
            if (ty == 0)      { if (k >= j) row = 561 + tidx[i][j] + (k - j); }   // triple (i,j,k)
            else if (ty == 1) { if (k <= i) row = 33 + pidx[k] + (i - k); }       // pair (k,i)
            else if (ty == 2) { row = 1 + k; }                                    // linear z_k
            s.rt[gg * 8 + jj] = (short)row;
        }
    }
    // [NGRAN,NGP): mg stays 0 -> pipeline overreads hit zs[0][0][m], never used
    return s;
}
constexpr Sched S = make_sched();
static_assert(S.nq[0] == 36 && S.nq[1] == 84 && S.nq[2] == 160 && S.nq[3] == 272, "chunk counts");

// ---- prep (R7-proven structure): coalesced, block per 4 granules; B -> fp16 RNE ----
__global__ void sindy_prep(const float* __restrict__ Xi,
                           const float* __restrict__ Xi_mask,
                           uint2* __restrict__ Bp2, size_t ws_size) {
    __shared__ unsigned short sh[8][32];
    const int tid = threadIdx.x;
    const int jj = tid >> 5, n = tid & 31;
#pragma unroll
    for (int pass = 0; pass < 4; ++pass) {
        int g = blockIdx.x * 4 + pass;
        int row = S.rt[g * 8 + jj];
        float f = 0.0f;
        if (row >= 0) f = Xi[row * Z + n] * Xi_mask[row * Z + n];
        _Float16 hh = (_Float16)f;                       // RNE f32->f16
        sh[jj][n] = __builtin_bit_cast(unsigned short, hh);
        __syncthreads();
        if (tid < 64) {
            int n2 = tid & 31, rep = tid >> 5;
            unsigned v0 = sh[4*rep+0][n2], v1 = sh[4*rep+1][n2];
            unsigned v2 = sh[4*rep+2][n2], v3 = sh[4*rep+3][n2];
            int c = g >> 1, h = g & 1;
            size_t idx = ((size_t)c * 64 + h * 32 + n2) * 2 + rep;
            if ((idx + 1) * 8 <= ws_size)
                Bp2[idx] = uint2{v0 | (v1 << 16), v2 | (v3 << 16)};
        }
        __syncthreads();
    }
}

// ---- main: block = 2 tiles x 4 k-splits; wave = BOTH tiles, one k-split ----
__global__ __launch_bounds__(256, 4) void sindy_mfma(const float* __restrict__ z,
                                                     const float* __restrict__ Xi,
                                                     const float* __restrict__ Xi_mask,
                                                     const uint4* __restrict__ Bp,
                                                     float* __restrict__ out) {
    const int lane = threadIdx.x & 63;
    const int kh = threadIdx.x >> 6;     // k-split 0..3 (= wave id)
    const int m = lane & 31;
    const int half = lane >> 5;
    const long R = (long)blockIdx.x * 64;   // rows of tile0; tile1 = R+32

    __shared__ float zs[33][2][32];      // interleaved: zs[k][tile][m]; bank = m
    __shared__ float cs[2][32][32];      // sequential-add combine (2 tiles)
    __shared__ unsigned mg_sh[NGP];

    for (int t = threadIdx.x; t < NGP; t += 256) mg_sh[t] = S.mg[t];
    // stage z for 64 rows (coalesced float4 reads)
    for (int idx = threadIdx.x; idx < 512; idx += 256) {
        int row = idx >> 3, q4 = idx & 7;
        float4 v = ((const float4*)(z + (R + row) * Z))[q4];
        int t = row >> 5, mm = row & 31;
        zs[4*q4+0][t][mm] = v.x; zs[4*q4+1][t][mm] = v.y;
        zs[4*q4+2][t][mm] = v.z; zs[4*q4+3][t][mm] = v.w;
    }
    if (threadIdx.x < 64) zs[32][threadIdx.x >> 5][threadIdx.x & 31] = 1.0f;  // z~[32]=1
    __syncthreads();

    const int c0 = kh * KSPAN;
    const char* zmb = (const char*)&zs[0][0][0] + 4 * m;   // tile0; tile1 = +128
    const unsigned* mgh = mg_sh + half;
    const uint4* bpl = Bp + lane;

    // B register double-buffer: bufA = chunk c, bufB = chunk c+1.
    // Plain global loads (L2-resident); compiler inserts counted vmcnt waits.
    uint4 bufA = bpl[(size_t)(c0 + 0) * 64];
    uint4 bufB = bpl[(size_t)(c0 + 1) * 64];

    // marching pointers (strength-reduced by hand; no clamps in the loop)
    const uint4* bptr = bpl + (size_t)(c0 + 2) * 64;   // chunk c+2; c+3 at +1024B imm
    const unsigned* mgp = mgh + 2 * c0 + 8;            // mg for iter+2; pair 8B apart

    // prime shallow pipeline (plain scalars, single scope — R9/R13-proven)
    unsigned u0 = mgh[2*c0], u1 = mgh[2*c0+2];
    float pA0, pA1, pB0, pB1;
    {
        float i0 = *(const float*)(zmb + (u0 & 0xFFFFu)), i1 = *(const float*)(zmb + (u0 & 0xFFFFu) + 128);
        float j0 = *(const float*)(zmb + (u0 >> 16)),     j1 = *(const float*)(zmb + (u0 >> 16) + 128);
        pA0 = i0 * j0; pA1 = i1 * j1;
        float e0 = *(const float*)(zmb + (u1 & 0xFFFFu)), e1 = *(const float*)(zmb + (u1 & 0xFFFFu) + 128);
        float f0 = *(const float*)(zmb + (u1 >> 16)),     f1 = *(const float*)(zmb + (u1 >> 16) + 128);
        pB0 = e0 * f0; pB1 = e1 * f1;
    }
    unsigned w0s = mgh[2*c0+4], w1s = mgh[2*c0+6];

    f32x16 acc0 = {}, acc1 = {};

    auto seg = [&](int Q, int cbeg, int cfin, bool tail) {
        // this quarter's z octets for both tiles, pre-packed to fp16 pairs
        // (RTZ; 11-bit trunc << old 8-bit bf16 trunc). reg q: lo=k 2q, hi=k 2q+1.
        const char* zq = zmb + Q * 2048;
        h2 zA0, zA1, zA2, zA3, zB0, zB1, zB2, zB3;
        {
            float a0 = *(const float*)(zq +    0), a1 = *(const float*)(zq +  256);
            float a2 = *(const float*)(zq +  512), a3 = *(const float*)(zq +  768);
            float a4 = *(const float*)(zq + 1024), a5 = *(const float*)(zq + 1280);
            float a6 = *(const float*)(zq + 1536), a7 = *(const float*)(zq + 1792);
            float b0 = *(const float*)(zq +  128), b1 = *(const float*)(zq +  384);
            float b2 = *(const float*)(zq +  640), b3 = *(const float*)(zq +  896);
            float b4 = *(const float*)(zq + 1152), b5 = *(const float*)(zq + 1408);
            float b6 = *(const float*)(zq + 1664), b7 = *(const float*)(zq + 1920);
            zA0 = pkrtz(a0, a1); zA1 = pkrtz(a2, a3);
            zA2 = pkrtz(a4, a5); zA3 = pkrtz(a6, a7);
            zB0 = pkrtz(b0, b1); zB1 = pkrtz(b2, b3);
            zB2 = pkrtz(b4, b5); zB3 = pkrtz(b6, b7);
        }

        auto mfma0 = [&](float pp, const uint4& bv) {   // tile0
            h2 p2 = pkrtz(pp, pp);
            union { h2 h[4]; h8 v; } a;
            a.h[0] = p2 * zA0; a.h[1] = p2 * zA1;
            a.h[2] = p2 * zA2; a.h[3] = p2 * zA3;
            union { uint4 v; h8 h; } b; b.v = bv;
            acc0 = __builtin_amdgcn_mfma_f32_32x32x16_f16(a.v, b.h, acc0, 0, 0, 0);
        };
        auto mfma1 = [&](float pp, const uint4& bv) {   // tile1
            h2 p2 = pkrtz(pp, pp);
            union { h2 h[4]; h8 v; } a;
            a.h[0] = p2 * zB0; a.h[1] = p2 * zB1;
            a.h[2] = p2 * zB2; a.h[3] = p2 * zB3;
            union { uint4 v; h8 h; } b; b.v = bv;
            acc1 = __builtin_amdgcn_mfma_f32_32x32x16_f16(a.v, b.h, acc1, 0, 0, 0);
        };

        const int cend = tail ? cfin - 2 : cfin;
#pragma unroll 2
        for (int c = cbeg; c < cend; c += 2) {
            // top: issue global loads for the NEXT pair (c+2, c+3) — marching
            // pointer, 2nd load folds to imm offset:1024. No clamp needed:
            // only kh3's final iteration would overrun, and it is peeled.
            uint4 nA = bptr[0];
            uint4 nB = bptr[64];
            bptr += 128;
            // stage 1: mg for iter+2 (pad absorbs overread) — ds_read2 pair
            unsigned nw0 = mgp[0], nw1 = mgp[2];
            mgp += 4;
            // stage 2: z reads for iter+1 — tile pairs 128 B apart (ds_read2)
            float a0i = *(const float*)(zmb + (w0s & 0xFFFFu));
            float a1i = *(const float*)(zmb + (w0s & 0xFFFFu) + 128);
            float a0j = *(const float*)(zmb + (w0s >> 16));
            float a1j = *(const float*)(zmb + (w0s >> 16) + 128);
            float b0i = *(const float*)(zmb + (w1s & 0xFFFFu));
            float b1i = *(const float*)(zmb + (w1s & 0xFFFFu) + 128);
            float b0j = *(const float*)(zmb + (w1s >> 16));
            float b1j = *(const float*)(zmb + (w1s >> 16) + 128);
            // 4 MFMAs: 2 chunks x 2 tiles, B shared per chunk
            mfma0(pA0, bufA); mfma1(pA1, bufA);
            mfma0(pB0, bufB); mfma1(pB1, bufB);
            // retire products + mg + B double-buffer
            pA0 = a0i * a0j; pA1 = a1i * a1j; pB0 = b0i * b0j; pB1 = b1i * b1j;
            w0s = nw0; w1s = nw1;
            bufA = nA; bufB = nB;
        }
        if (tail) {
            // peeled final iteration (kh3, chunks 550/551): consume-only —
            // no loads (would read past the table), no staging (discarded)
            mfma0(pA0, bufA); mfma1(pA1, bufA);
            mfma0(pB0, bufB); mfma1(pB1, bufB);
        }
    };

    // quarter-aligned pieces of this wave's [c0, c0+138) range
    if (kh == 0)      { seg(0,   0,  36, false); seg(1,  36, 120, false); seg(2, 120, 138, false); }
    else if (kh == 1) { seg(2, 138, 276, false); }
    else if (kh == 2) { seg(2, 276, 280, false); seg(3, 280, 414, false); }
    else              { seg(3, 414, 552, true); }

    // sequential-add combine: kh3 writes, kh2/kh1 add, kh0 finishes
    if (kh == 3) {
#pragma unroll
        for (int r = 0; r < 16; ++r) {
            int row = (r & 3) + 8 * (r >> 2) + 4 * half;
            cs[0][row][m] = acc0[r]; cs[1][row][m] = acc1[r];
        }
    }
    __syncthreads();
    if (kh == 2) {
#pragma unroll
        for (int r = 0; r < 16; ++r) {
            int row = (r & 3) + 8 * (r >> 2) + 4 * half;
            cs[0][row][m] += acc0[r]; cs[1][row][m] += acc1[r];
        }
    }
    __syncthreads();
    if (kh == 1) {
#pragma unroll
        for (int r = 0; r < 16; ++r) {
            int row = (r & 3) + 8 * (r >> 2) + 4 * half;
            cs[0][row][m] += acc0[r]; cs[1][row][m] += acc1[r];
        }
    }
    __syncthreads();
    if (kh == 0) {
        const float bias = Xi[m] * Xi_mask[m];   // library row 0 (ones), col n = m
        float* o0 = out + R * Z;
        float* o1 = out + (R + 32) * Z;
#pragma unroll
        for (int r = 0; r < 16; ++r) {
            int row = (r & 3) + 8 * (r >> 2) + 4 * half;
            o0[row * Z + m] = acc0[r] + cs[0][row][m] + bias;
            o1[row * Z + m] = acc1[r] + cs[1][row][m] + bias;
        }
    }
}

extern "C" void kernel_launch(void* const* d_in, const int* in_sizes, int n_in,
                              void* d_out, int out_size, void* d_ws, size_t ws_size,
                              hipStream_t stream) {
    const float* z       = (const float*)d_in[0];
    const float* Xi      = (const float*)d_in[1];
    const float* Xi_mask = (const float*)d_in[2];
    // d_in[3]=z_mean, d_in[4]=z_std: unused by the reference
    float* out = (float*)d_out;
    uint4* Bp  = (uint4*)d_ws;   // NCHUNK*64*16 = 565,248 bytes

    sindy_prep<<<NGRAN / 4, 256, 0, stream>>>(Xi, Xi_mask, (uint2*)d_ws, ws_size);
    sindy_mfma<<<NBLK, 256, 0, stream>>>(z, Xi, Xi_mask, Bp, out);
}